// Round 6
// baseline (61683.160 us; speedup 1.0000x reference)
//
#include <hip/hip_runtime.h>
#include <cmath>

#define VOCAB   4096
#define ENC_DIM 1024
#define PRED_H  640
#define JOINT_H 640
#define TMAX    128
#define MAX_SYM 30
#define NSTEPS  (TMAX*(MAX_SYM+1))   // 3968
#define NWG     128
#define NTHR    512
#define RLX __ATOMIC_RELAXED
#define AGT __HIP_MEMORY_SCOPE_AGENT

typedef unsigned long long u64;
typedef __attribute__((ext_vector_type(4))) unsigned int uint4v;

// ws layout (bytes):
//   0     : parts[128] u64 (tagged argmax entries)                [0,1024)
//   4096  : bufsT[1280] u64: h0n(640) | h1n(640) tagged           [4096,14336)
//   14336 : hidT[640] u64 tagged                                  [14336,19456)
// tagged word = (tag u32 << 32) | f32 bits. tag = s+1 (>=1; 0 = unwritten)

__device__ __forceinline__ float wave_red(float v){
  v += __shfl_xor(v, 32, 64);
  v += __shfl_xor(v, 16, 64);
  v += __shfl_xor(v,  8, 64);
  v += __shfl_xor(v,  4, 64);
  v += __shfl_xor(v,  2, 64);
  v += __shfl_xor(v,  1, 64);
  return v;
}

__device__ __forceinline__ float sigf(float x){ return 1.0f/(1.0f+expf(-x)); }

__device__ __forceinline__ void tstore(u64* p, float v, unsigned tag){
  __hip_atomic_store(p, ((u64)tag<<32) | (u64)__float_as_uint(v), RLX, AGT);
}

// 16B coherent load of two tagged u64s (bypasses L1/L2 like sc-scoped atomics).
__device__ __forceinline__ uint4v tload2(const u64* p){
  uint4v r;
  asm volatile("global_load_dwordx4 %0, %1, off sc0 sc1\n\t"
               "s_waitcnt vmcnt(0)"
               : "=v"(r) : "v"(p) : "memory");
  return r;
}

// Poll n_u64 (even) tagged words into LDS floats. Fallback path guarantees
// progress even if the wide-load coherence path ever misbehaves.
__device__ __forceinline__ void poll_vec(u64* src, float* dst, int n_u64,
                                         unsigned tag, int tid){
  for (int i = tid; i < (n_u64 >> 1); i += NTHR){
    u64* p = src + 2*i;
    int spins = 0;
    for(;;){
      uint4v v = tload2(p);
      if (v.y == tag && v.w == tag){
        dst[2*i]   = __uint_as_float(v.x);
        dst[2*i+1] = __uint_as_float(v.z);
        break;
      }
      __builtin_amdgcn_s_sleep(2);
      if (++spins > (1<<20)){
        u64 a = __hip_atomic_load(p,   RLX, AGT);
        u64 b = __hip_atomic_load(p+1, RLX, AGT);
        if ((unsigned)(a>>32) == tag && (unsigned)(b>>32) == tag){
          dst[2*i]   = __uint_as_float((unsigned)a);
          dst[2*i+1] = __uint_as_float((unsigned)b);
          break;
        }
        spins = 0;
      }
    }
  }
}

// argmax entry: key(32b order-preserving) << 24 | (tag&0xFFF)<<12 | (4095-r)
__device__ __forceinline__ u64 mkentry(float lg, int r, unsigned ep){
  unsigned u = __float_as_uint(lg);
  u = (u & 0x80000000u) ? ~u : (u | 0x80000000u);
  return ((u64)u<<24) | ((u64)(ep&0xFFFu)<<12) | (u64)(4095 - r);
}

__global__ void init_ws(unsigned* ws){
  for (int i = threadIdx.x; i < 8192; i += 256) ws[i] = 0u;   // 32 KB
}

__global__ __launch_bounds__(NTHR, 2)
void rnnt_decode(const float* __restrict__ enc,
                 const int*   __restrict__ outlen_p,
                 const float* __restrict__ emb,
                 const float* __restrict__ Wih0, const float* __restrict__ Whh0, const float* __restrict__ b0,
                 const float* __restrict__ Wih1, const float* __restrict__ Whh1, const float* __restrict__ b1,
                 const float* __restrict__ Wj1,  const float* __restrict__ bj1,
                 const float* __restrict__ Wj2,  const float* __restrict__ bj2,
                 float* __restrict__ out,
                 u64* __restrict__ parts,        // [128]
                 u64* __restrict__ bufsT,        // [2*PRED_H]
                 u64* __restrict__ hidT)         // [JOINT_H]
{
  const int wg = blockIdx.x, tid = threadIdx.x;
  const int wave = tid >> 6, lane = tid & 63;
  const int timesteps = outlen_p[0];

  __shared__ float xa[PRED_H];
  __shared__ float xsh[ENC_DIM];
  __shared__ float h0buf[2][PRED_H];
  __shared__ float h1buf[2][PRED_H];
  __shared__ float hidsh[JOINT_H];
  __shared__ float zsh[4][5];
  __shared__ float zjs[8][3];
  __shared__ float c0c[5], c1c[5], c0p[5], c1p[5];
  __shared__ float bj1sh[5];
  __shared__ u64 psh[8];
  __shared__ int kshm;

  const int jb = wg*5;   // exactly 5 j per WG (640/128)

  // ---- LSTM rows: 20 per WG; ri -> gate=ri&3, jloc=ri>>2.
  // wave handles ri = wave, wave+8, and (wave<4) wave+16.
  float w0x[3][10], w0h[3][10], w1x[3][10], w1h[3][10];
  float bL0[3], bL1[3];
  #pragma unroll
  for (int rr = 0; rr < 3; ++rr){
    int ri = wave + (rr<<3);
    bool act = (rr < 2) || (wave < 4);
    int row = act ? ((ri&3)*PRED_H + jb + (ri>>2)) : 0;
    #pragma unroll
    for (int i = 0; i < 10; ++i){
      int c = lane + (i<<6);
      w0x[rr][i] = act ? Wih0[(size_t)row*PRED_H + c] : 0.f;
      w0h[rr][i] = act ? Whh0[(size_t)row*PRED_H + c] : 0.f;
      w1x[rr][i] = act ? Wih1[(size_t)row*PRED_H + c] : 0.f;
      w1h[rr][i] = act ? Whh1[(size_t)row*PRED_H + c] : 0.f;
    }
    bL0[rr] = act ? b0[row] : 0.f;
    bL1[rr] = act ? b1[row] : 0.f;
  }

  // ---- Joint1: rows jb+2p+grp (grp = wave>>2; w03: p=0,1,2; w47: p=0,1)
  const int grp = wave >> 2;
  const int vt  = ((wave & 3)<<6) | lane;   // 0..255
  const int nrows = grp ? 2 : 3;
  float wjf[3][4], wjh[3][3], ca[3];
  #pragma unroll
  for (int p = 0; p < 3; ++p){
    ca[p] = 0.f;
    bool act = p < nrows;
    int r = act ? (jb + 2*p + grp) : 0;
    #pragma unroll
    for (int i = 0; i < 4; ++i)
      wjf[p][i] = act ? Wj1[(size_t)r*(ENC_DIM+PRED_H) + vt + (i<<8)] : 0.f;
    #pragma unroll
    for (int i = 0; i < 3; ++i){
      int c = vt + (i<<8);
      wjh[p][i] = (act && c < PRED_H) ? Wj1[(size_t)r*(ENC_DIM+PRED_H) + ENC_DIM + c] : 0.f;
    }
  }

  // ---- Joint2: 32 rows per WG, 4 per wave (consecutive)
  const int r2b = (wg<<5) + (wave<<2);
  float wj2[4][10], bj2r[4];
  #pragma unroll
  for (int q = 0; q < 4; ++q){
    #pragma unroll
    for (int i = 0; i < 10; ++i)
      wj2[q][i] = Wj2[(size_t)(r2b+q)*JOINT_H + lane + (i<<6)];
    bj2r[q] = bj2[r2b+q];
  }

  for (int i = tid; i < PRED_H; i += NTHR){ h0buf[0][i] = 0.f; h1buf[0][i] = 0.f; }
  if (tid < 5){ c0c[tid] = 0.f; c1c[tid] = 0.f; bj1sh[tid] = bj1[jb+tid]; }
  __syncthreads();

  int cur = 0, t = 0, sa = 0, last = -1, cnt = 0, tStaged = -1;
  bool done = false, reuse = false;

  for (int s = 0; s < NSTEPS; ++s){
    if (done){
      if (wg < 8) out[(size_t)s*VOCAB + wg*NTHR + tid] = 0.f;
      continue;
    }
    const unsigned tag = (unsigned)(s + 1);

    if (!reuse){
      // ===== A: LSTM layer 0 (inputs all LDS-local) =====
      for (int i = tid; i < PRED_H; i += NTHR)
        xa[i] = (last >= 0) ? emb[(size_t)last*PRED_H + i] : 0.f;
      __syncthreads();
      #pragma unroll
      for (int rr = 0; rr < 3; ++rr){
        bool act = (rr < 2) || (wave < 4);
        if (act){
          int ri = wave + (rr<<3);
          float acc = 0.f;
          #pragma unroll
          for (int i = 0; i < 10; ++i) acc = fmaf(w0x[rr][i], xa[lane+(i<<6)], acc);
          #pragma unroll
          for (int i = 0; i < 10; ++i) acc = fmaf(w0h[rr][i], h0buf[cur][lane+(i<<6)], acc);
          acc = wave_red(acc);
          if (lane == 0) zsh[ri&3][ri>>2] = acc + bL0[rr];
        }
      }
      __syncthreads();
      if (tid < 5){
        float ig = sigf(zsh[0][tid]), fg = sigf(zsh[1][tid]);
        float gg = tanhf(zsh[2][tid]), og = sigf(zsh[3][tid]);
        float c2 = fg*c0c[tid] + ig*gg;
        c0p[tid] = c2;
        tstore(&bufsT[jb+tid], og*tanhf(c2), tag);
      }
      __syncthreads();

      // ===== B: LSTM layer 1 =====
      poll_vec(bufsT, h0buf[cur^1], PRED_H, tag, tid);   // h0n (1 RTT)
      __syncthreads();
      #pragma unroll
      for (int rr = 0; rr < 3; ++rr){
        bool act = (rr < 2) || (wave < 4);
        if (act){
          int ri = wave + (rr<<3);
          float acc = 0.f;
          #pragma unroll
          for (int i = 0; i < 10; ++i) acc = fmaf(w1x[rr][i], h0buf[cur^1][lane+(i<<6)], acc);
          #pragma unroll
          for (int i = 0; i < 10; ++i) acc = fmaf(w1h[rr][i], h1buf[cur][lane+(i<<6)], acc);
          acc = wave_red(acc);
          if (lane == 0) zsh[ri&3][ri>>2] = acc + bL1[rr];
        }
      }
      __syncthreads();
      if (tid < 5){
        float ig = sigf(zsh[0][tid]), fg = sigf(zsh[1][tid]);
        float gg = tanhf(zsh[2][tid]), og = sigf(zsh[3][tid]);
        float c2 = fg*c1c[tid] + ig*gg;
        c1p[tid] = c2;
        tstore(&bufsT[PRED_H+jb+tid], og*tanhf(c2), tag);
      }
    }

    // ===== C: joint hidden =====
    {
      int tcap = (t < TMAX-1) ? t : (TMAX-1);
      bool fNew = (tcap != tStaged);
      if (fNew)
        for (int i = tid; i < ENC_DIM; i += NTHR) xsh[i] = enc[(size_t)tcap*ENC_DIM + i];
      if (!reuse)
        poll_vec(bufsT + PRED_H, h1buf[cur^1], PRED_H, tag, tid);  // h1n (1 RTT)
      __syncthreads();
      if (fNew){
        #pragma unroll
        for (int p = 0; p < 3; ++p){
          if (p < nrows){
            float a = 0.f;
            #pragma unroll
            for (int i = 0; i < 4; ++i) a = fmaf(wjf[p][i], xsh[vt+(i<<8)], a);
            ca[p] = a;
          }
        }
        tStaged = tcap;
      }
      #pragma unroll
      for (int p = 0; p < 3; ++p){
        if (p < nrows){
          float acc = ca[p];
          #pragma unroll
          for (int i = 0; i < 3; ++i){
            int c = vt + (i<<8);
            acc = fmaf(wjh[p][i], h1buf[cur^1][(c < PRED_H) ? c : 0], acc);
          }
          acc = wave_red(acc);
          if (lane == 0) zjs[wave][p] = acc;
        }
      }
      __syncthreads();
      if (tid < 5){
        int p = tid >> 1, g = tid & 1;
        float v = zjs[(g<<2)][p] + zjs[(g<<2)+1][p] + zjs[(g<<2)+2][p] + zjs[(g<<2)+3][p]
                + bj1sh[tid];
        tstore(&hidT[jb+tid], v > 0.f ? v : 0.f, tag);
      }
    }

    // ===== D: logits + argmax =====
    int k;
    {
      poll_vec(hidT, hidsh, JOINT_H, tag, tid);          // hid (1 RTT)
      __syncthreads();
      float a0 = 0.f, a1 = 0.f, a2 = 0.f, a3 = 0.f;
      #pragma unroll
      for (int i = 0; i < 10; ++i){
        float h = hidsh[lane+(i<<6)];
        a0 = fmaf(wj2[0][i], h, a0);
        a1 = fmaf(wj2[1][i], h, a1);
        a2 = fmaf(wj2[2][i], h, a2);
        a3 = fmaf(wj2[3][i], h, a3);
      }
      a0 = wave_red(a0); a1 = wave_red(a1); a2 = wave_red(a2); a3 = wave_red(a3);
      if (lane == 0){
        float l0 = a0 + bj2r[0], l1 = a1 + bj2r[1], l2 = a2 + bj2r[2], l3 = a3 + bj2r[3];
        *(float4*)(out + (size_t)s*VOCAB + r2b) = make_float4(l0, l1, l2, l3);
        u64 m = mkentry(l0, r2b, tag);
        u64 e = mkentry(l1, r2b+1, tag); if (e > m) m = e;
        e = mkentry(l2, r2b+2, tag);     if (e > m) m = e;
        e = mkentry(l3, r2b+3, tag);     if (e > m) m = e;
        psh[wave] = m;
      }
      __syncthreads();
      if (tid == 0){
        u64 m = psh[0];
        #pragma unroll
        for (int w = 1; w < 8; ++w) if (psh[w] > m) m = psh[w];
        __hip_atomic_store(&parts[wg], m, RLX, AGT);
      }
      // one-wave gather of 128 partials (64 paired loads), butterfly max
      if (wave == 0){
        u64* p = &parts[lane<<1];
        u64 e0, e1;
        int spins = 0;
        for(;;){
          uint4v v = tload2(p);
          if ((((v.x>>12)&0xFFFu) == (tag&0xFFFu)) &&
              (((v.z>>12)&0xFFFu) == (tag&0xFFFu))){
            e0 = ((u64)v.y<<32) | v.x;
            e1 = ((u64)v.w<<32) | v.z;
            break;
          }
          __builtin_amdgcn_s_sleep(2);
          if (++spins > (1<<20)){
            u64 a = __hip_atomic_load(p,   RLX, AGT);
            u64 b = __hip_atomic_load(p+1, RLX, AGT);
            if ((((unsigned)(a>>12))&0xFFFu) == (tag&0xFFFu) &&
                (((unsigned)(b>>12))&0xFFFu) == (tag&0xFFFu)){ e0 = a; e1 = b; break; }
            spins = 0;
          }
        }
        u64 m = e0 > e1 ? e0 : e1;
        #pragma unroll
        for (int off = 32; off; off >>= 1){
          u64 o = __shfl_xor(m, off, 64);
          if (o > m) m = o;
        }
        if (lane == 0) kshm = 4095 - (int)(m & 0xFFFull);
      }
      __syncthreads();
      k = kshm;
    }

    // ===== E: decision (replicated in every WG) =====
    bool stop = (k == 0) || (sa >= MAX_SYM);
    if (!stop){
      if (wg == 0 && tid == 0) out[(size_t)NSTEPS*VOCAB + cnt] = (float)k;
      if (tid < 5){ c0c[tid] = c0p[tid]; c1c[tid] = c1p[tid]; }
      cnt++; sa++; last = k; cur ^= 1; reuse = false;
    } else {
      sa = 0; t++; reuse = true;
      if (t >= timesteps) done = true;
    }
    __syncthreads();
  }

  // labels tail (-1) and cnt
  size_t lab = (size_t)NSTEPS*VOCAB;
  int gidx = wg*NTHR + tid;
  for (int i = cnt + gidx; i < NSTEPS; i += NWG*NTHR) out[lab + i] = -1.f;
  if (wg == 0 && tid == 0) out[lab + NSTEPS] = (float)cnt;
}

extern "C" void kernel_launch(void* const* d_in, const int* in_sizes, int n_in,
                              void* d_out, int out_size, void* d_ws, size_t ws_size,
                              hipStream_t stream) {
  const float* enc  = (const float*)d_in[0];
  const int*   olen = (const int*)  d_in[1];
  const float* emb  = (const float*)d_in[2];
  const float* Wih0 = (const float*)d_in[3];
  const float* Whh0 = (const float*)d_in[4];
  const float* b0   = (const float*)d_in[5];
  const float* Wih1 = (const float*)d_in[6];
  const float* Whh1 = (const float*)d_in[7];
  const float* b1   = (const float*)d_in[8];
  const float* Wj1  = (const float*)d_in[9];
  const float* bj1  = (const float*)d_in[10];
  const float* Wj2  = (const float*)d_in[11];
  const float* bj2  = (const float*)d_in[12];
  float* out = (float*)d_out;

  u64* parts = (u64*)d_ws;
  u64* bufsT = (u64*)((char*)d_ws + 4096);
  u64* hidT  = (u64*)((char*)d_ws + 14336);

  init_ws<<<1, 256, 0, stream>>>((unsigned*)d_ws);

  void* args[] = {&enc,&olen,&emb,&Wih0,&Whh0,&b0,&Wih1,&Whh1,&b1,
                  &Wj1,&bj1,&Wj2,&bj2,&out,&parts,&bufsT,&hidT};
  hipLaunchCooperativeKernel((const void*)rnnt_decode, dim3(NWG), dim3(NTHR),
                             args, 0, stream);
}

// Round 7
// 56057.983 us; speedup vs baseline: 1.1003x; 1.1003x over previous
//
#include <hip/hip_runtime.h>
#include <cmath>

#define VOCAB   4096
#define ENC_DIM 1024
#define PRED_H  640
#define JOINT_H 640
#define TMAX    128
#define MAX_SYM 30
#define NSTEPS  (TMAX*(MAX_SYM+1))   // 3968
#define NWG     256
#define NTHR    512
#define NREP    8
#define RLX __ATOMIC_RELAXED
#define AGT __HIP_MEMORY_SCOPE_AGENT

typedef unsigned long long u64;

// ws layout (bytes), all 8-replica tagged arrays:
//   0      : parts [8][256] u64   (tagged argmax entries)    [0,16384)
//   16384  : bufsT [8][1280] u64  (h0n 640 | h1n 640)        [16384,98304)
//   98304  : hidT  [8][640] u64                              [98304,139264)
// tagged word = (tag u32 << 32) | f32 bits. tag = s+1 (>=1; 0/stale = not ready)

__device__ __forceinline__ float wave_red(float v){
  v += __shfl_xor(v, 32, 64);
  v += __shfl_xor(v, 16, 64);
  v += __shfl_xor(v,  8, 64);
  v += __shfl_xor(v,  4, 64);
  v += __shfl_xor(v,  2, 64);
  v += __shfl_xor(v,  1, 64);
  return v;
}

__device__ __forceinline__ float sigf(float x){ return 1.0f/(1.0f+expf(-x)); }

// store one element to all 8 replicas (fire-and-forget)
__device__ __forceinline__ void tstore8(u64* base, int stride, int idx,
                                        float v, unsigned tag){
  u64 w = ((u64)tag<<32) | (u64)__float_as_uint(v);
  #pragma unroll
  for (int r = 0; r < NREP; ++r)
    __hip_atomic_store(base + r*stride + idx, w, RLX, AGT);
}

__device__ __forceinline__ float tpollv(u64* p, unsigned tag){
  u64 e = __hip_atomic_load(p, RLX, AGT);
  while ((unsigned)(e>>32) != tag){
    __builtin_amdgcn_s_sleep(2);
    e = __hip_atomic_load(p, RLX, AGT);
  }
  return __uint_as_float((unsigned)e);
}

// argmax entry: key(32b order-preserving) << 24 | (tag&0xFFF)<<12 | (4095-r)
__device__ __forceinline__ u64 mkentry(float lg, int r, unsigned ep){
  unsigned u = __float_as_uint(lg);
  u = (u & 0x80000000u) ? ~u : (u | 0x80000000u);
  return ((u64)u<<24) | ((u64)(ep&0xFFFu)<<12) | (u64)(4095 - r);
}

__global__ void init_ws(unsigned* ws){
  int i = blockIdx.x*blockDim.x + threadIdx.x;
  for (; i < 34816; i += gridDim.x*blockDim.x) ws[i] = 0u;   // 139264 B
}

__global__ __launch_bounds__(NTHR, 2)
void rnnt_decode(const float* __restrict__ enc,
                 const int*   __restrict__ outlen_p,
                 const float* __restrict__ emb,
                 const float* __restrict__ Wih0, const float* __restrict__ Whh0, const float* __restrict__ b0,
                 const float* __restrict__ Wih1, const float* __restrict__ Whh1, const float* __restrict__ b1,
                 const float* __restrict__ Wj1,  const float* __restrict__ bj1,
                 const float* __restrict__ Wj2,  const float* __restrict__ bj2,
                 float* __restrict__ out,
                 u64* __restrict__ parts,        // [8][256]
                 u64* __restrict__ bufsT,        // [8][1280]
                 u64* __restrict__ hidT)         // [8][640]
{
  const int wg = blockIdx.x, tid = threadIdx.x;
  const int wave = tid >> 6, lane = tid & 63;
  const int timesteps = outlen_p[0];
  const int rep = wg >> 5;                 // my replica
  u64* myParts = parts + rep*256;
  u64* myBufs  = bufsT + rep*1280;
  u64* myHid   = hidT  + rep*640;

  __shared__ float xa[PRED_H];
  __shared__ float xsh[ENC_DIM];
  __shared__ float h0buf[2][PRED_H];
  __shared__ float h1buf[2][PRED_H];
  __shared__ float hidsh[JOINT_H];
  __shared__ float zsh[4][4];
  __shared__ float zjs[8];
  __shared__ float c0c[4], c1c[4], c0p[4], c1p[4];
  __shared__ u64 psh[8];
  __shared__ u64 pmx[4];

  const int jb = (wg*PRED_H)/NWG;
  const int je = ((wg+1)*PRED_H)/NWG;
  const int nj = je - jb;                 // 2 or 3

  // ---- persistent LSTM weight registers (identical mapping to R5) ----
  const int riA = wave, riB = wave + 8;
  const int gA = riA & 3, jA = riA >> 2;
  const int gB = riB & 3, jBx = riB >> 2;
  const bool hasB = (riB < 4*nj);
  const int rowA = gA*PRED_H + jb + jA;
  const int rowB = hasB ? (gB*PRED_H + jb + jBx) : 0;

  float w0xA[10], w0hA[10], w0xB[10], w0hB[10];
  float w1xA[10], w1hA[10], w1xB[10], w1hB[10];
  #pragma unroll
  for (int i = 0; i < 10; ++i){
    int c = lane + (i<<6);
    w0xA[i] = Wih0[(size_t)rowA*PRED_H + c];
    w0hA[i] = Whh0[(size_t)rowA*PRED_H + c];
    w1xA[i] = Wih1[(size_t)rowA*PRED_H + c];
    w1hA[i] = Whh1[(size_t)rowA*PRED_H + c];
    w0xB[i] = hasB ? Wih0[(size_t)rowB*PRED_H + c] : 0.f;
    w0hB[i] = hasB ? Whh0[(size_t)rowB*PRED_H + c] : 0.f;
    w1xB[i] = hasB ? Wih1[(size_t)rowB*PRED_H + c] : 0.f;
    w1hB[i] = hasB ? Whh1[(size_t)rowB*PRED_H + c] : 0.f;
  }
  const float bA0 = b0[rowA], bA1 = b1[rowA];
  const float bB0 = hasB ? b0[rowB] : 0.f, bB1 = hasB ? b1[rowB] : 0.f;

  // ---- Wj1 per-role (waves 0-3: rows jb, jb+2; waves 4-7: row jb+1) ----
  const int vt = (wave < 4) ? wave*64 + lane : (wave-4)*64 + lane;  // 0..255
  float wjf0[4], wjh0[3], wjf2[4], wjh2[3];
  {
    int r0 = (wave < 4) ? jb : jb + 1;
    #pragma unroll
    for (int i = 0; i < 4; ++i) wjf0[i] = Wj1[(size_t)r0*(ENC_DIM+PRED_H) + vt + (i<<8)];
    #pragma unroll
    for (int i = 0; i < 3; ++i){
      int c = vt + (i<<8);
      wjh0[i] = (c < PRED_H) ? Wj1[(size_t)r0*(ENC_DIM+PRED_H) + ENC_DIM + c] : 0.f;
    }
    #pragma unroll
    for (int i = 0; i < 4; ++i) wjf2[i] = 0.f;
    #pragma unroll
    for (int i = 0; i < 3; ++i) wjh2[i] = 0.f;
    if (wave < 4 && nj == 3){
      int r2 = jb + 2;
      #pragma unroll
      for (int i = 0; i < 4; ++i) wjf2[i] = Wj1[(size_t)r2*(ENC_DIM+PRED_H) + vt + (i<<8)];
      #pragma unroll
      for (int i = 0; i < 3; ++i){
        int c = vt + (i<<8);
        wjh2[i] = (c < PRED_H) ? Wj1[(size_t)r2*(ENC_DIM+PRED_H) + ENC_DIM + c] : 0.f;
      }
    }
  }
  float bjr[3];
  bjr[0] = bj1[jb]; bjr[1] = bj1[jb+1]; bjr[2] = (nj == 3) ? bj1[jb+2] : 0.f;
  float ca0 = 0.f, ca2 = 0.f;

  // ---- Wj2: 16 rows per WG, 2 per wave ----
  const int rA2 = wg*16 + wave*2, rB2 = rA2 + 1;
  float wj2A[10], wj2B[10];
  #pragma unroll
  for (int i = 0; i < 10; ++i){
    int c = lane + (i<<6);
    wj2A[i] = Wj2[(size_t)rA2*JOINT_H + c];
    wj2B[i] = Wj2[(size_t)rB2*JOINT_H + c];
  }
  const float bjA2 = bj2[rA2], bjB2 = bj2[rB2];

  for (int i = tid; i < PRED_H; i += NTHR){ h0buf[0][i] = 0.f; h1buf[0][i] = 0.f; }
  if (tid < 4){ c0c[tid] = 0.f; c1c[tid] = 0.f; }
  __syncthreads();

  int cur = 0, t = 0, sa = 0, last = -1, cnt = 0, tStaged = -1;
  bool done = false, reuse = false;

  for (int s = 0; s < NSTEPS; ++s){
    if (done){
      if (wg < 8) out[(size_t)s*VOCAB + wg*NTHR + tid] = 0.f;
      continue;
    }
    const unsigned tag = (unsigned)(s + 1);

    if (!reuse){
      // ===== A: LSTM layer 0 (inputs all LDS-local) =====
      for (int i = tid; i < PRED_H; i += NTHR)
        xa[i] = (last >= 0) ? emb[(size_t)last*PRED_H + i] : 0.f;
      __syncthreads();
      {
        float acc = 0.f;
        #pragma unroll
        for (int i = 0; i < 10; ++i) acc = fmaf(w0xA[i], xa[lane+(i<<6)], acc);
        #pragma unroll
        for (int i = 0; i < 10; ++i) acc = fmaf(w0hA[i], h0buf[cur][lane+(i<<6)], acc);
        acc = wave_red(acc);
        if (lane == 0) zsh[gA][jA] = acc + bA0;
        if (hasB){
          float a2 = 0.f;
          #pragma unroll
          for (int i = 0; i < 10; ++i) a2 = fmaf(w0xB[i], xa[lane+(i<<6)], a2);
          #pragma unroll
          for (int i = 0; i < 10; ++i) a2 = fmaf(w0hB[i], h0buf[cur][lane+(i<<6)], a2);
          a2 = wave_red(a2);
          if (lane == 0) zsh[gB][jBx] = a2 + bB0;
        }
      }
      __syncthreads();
      if (tid < nj){
        float ig = sigf(zsh[0][tid]), fg = sigf(zsh[1][tid]);
        float gg = tanhf(zsh[2][tid]), og = sigf(zsh[3][tid]);
        float c2 = fg*c0c[tid] + ig*gg;
        c0p[tid] = c2;
        tstore8(bufsT, 1280, jb+tid, og*tanhf(c2), tag);
      }
      __syncthreads();

      // ===== B: LSTM layer 1 =====
      for (int i = tid; i < PRED_H; i += NTHR)
        h0buf[cur^1][i] = tpollv(&myBufs[i], tag);          // h0n (1 RTT, 32 pollers)
      __syncthreads();
      {
        float acc = 0.f;
        #pragma unroll
        for (int i = 0; i < 10; ++i) acc = fmaf(w1xA[i], h0buf[cur^1][lane+(i<<6)], acc);
        #pragma unroll
        for (int i = 0; i < 10; ++i) acc = fmaf(w1hA[i], h1buf[cur][lane+(i<<6)], acc);
        acc = wave_red(acc);
        if (lane == 0) zsh[gA][jA] = acc + bA1;
        if (hasB){
          float a2 = 0.f;
          #pragma unroll
          for (int i = 0; i < 10; ++i) a2 = fmaf(w1xB[i], h0buf[cur^1][lane+(i<<6)], a2);
          #pragma unroll
          for (int i = 0; i < 10; ++i) a2 = fmaf(w1hB[i], h1buf[cur][lane+(i<<6)], a2);
          a2 = wave_red(a2);
          if (lane == 0) zsh[gB][jBx] = a2 + bB1;
        }
      }
      __syncthreads();
      if (tid < nj){
        float ig = sigf(zsh[0][tid]), fg = sigf(zsh[1][tid]);
        float gg = tanhf(zsh[2][tid]), og = sigf(zsh[3][tid]);
        float c2 = fg*c1c[tid] + ig*gg;
        c1p[tid] = c2;
        tstore8(bufsT, 1280, PRED_H+jb+tid, og*tanhf(c2), tag);
      }
    }

    // ===== C: joint hidden =====
    {
      int tcap = (t < TMAX-1) ? t : (TMAX-1);
      bool fNew = (tcap != tStaged);
      if (fNew)
        for (int i = tid; i < ENC_DIM; i += NTHR) xsh[i] = enc[(size_t)tcap*ENC_DIM + i];
      if (!reuse)
        for (int i = tid; i < PRED_H; i += NTHR)
          h1buf[cur^1][i] = tpollv(&myBufs[PRED_H+i], tag);  // h1n (1 RTT)
      __syncthreads();
      if (fNew){
        float a = 0.f;
        #pragma unroll
        for (int i = 0; i < 4; ++i) a = fmaf(wjf0[i], xsh[vt+(i<<8)], a);
        ca0 = a;
        if (wave < 4 && nj == 3){
          float a2 = 0.f;
          #pragma unroll
          for (int i = 0; i < 4; ++i) a2 = fmaf(wjf2[i], xsh[vt+(i<<8)], a2);
          ca2 = a2;
        }
        tStaged = tcap;
      }
      {
        float acc = ca0;
        #pragma unroll
        for (int i = 0; i < 3; ++i){
          int c = vt + (i<<8);
          acc = fmaf(wjh0[i], h1buf[cur^1][(c < PRED_H) ? c : 0], acc);
        }
        acc = wave_red(acc);
        if (lane == 0) zjs[wave] = acc;
      }
      __syncthreads();
      if (tid == 0){
        float v0 = zjs[0]+zjs[1]+zjs[2]+zjs[3] + bjr[0];
        tstore8(hidT, 640, jb,   v0 > 0.f ? v0 : 0.f, tag);
        float v1 = zjs[4]+zjs[5]+zjs[6]+zjs[7] + bjr[1];
        tstore8(hidT, 640, jb+1, v1 > 0.f ? v1 : 0.f, tag);
      }
      if (nj == 3){
        __syncthreads();
        if (wave < 4){
          float acc = ca2;
          #pragma unroll
          for (int i = 0; i < 3; ++i){
            int c = vt + (i<<8);
            acc = fmaf(wjh2[i], h1buf[cur^1][(c < PRED_H) ? c : 0], acc);
          }
          acc = wave_red(acc);
          if (lane == 0) zjs[wave] = acc;
        }
        __syncthreads();
        if (tid == 0){
          float v2 = zjs[0]+zjs[1]+zjs[2]+zjs[3] + bjr[2];
          tstore8(hidT, 640, jb+2, v2 > 0.f ? v2 : 0.f, tag);
        }
      }
    }

    // ===== D: logits + argmax (replicated parts all-gather) =====
    int k;
    {
      for (int i = tid; i < JOINT_H; i += NTHR)
        hidsh[i] = tpollv(&myHid[i], tag);                   // hid (1 RTT)
      __syncthreads();
      float accA = 0.f, accB = 0.f;
      #pragma unroll
      for (int i = 0; i < 10; ++i){
        float h = hidsh[lane+(i<<6)];
        accA = fmaf(wj2A[i], h, accA);
        accB = fmaf(wj2B[i], h, accB);
      }
      accA = wave_red(accA);
      accB = wave_red(accB);
      if (lane == 0){
        float lgA = accA + bjA2, lgB = accB + bjB2;
        out[(size_t)s*VOCAB + rA2] = lgA;
        out[(size_t)s*VOCAB + rB2] = lgB;
        u64 eA = mkentry(lgA, rA2, tag), eB = mkentry(lgB, rB2, tag);
        psh[wave] = eA > eB ? eA : eB;
      }
      __syncthreads();
      if (tid == 0){
        u64 m = psh[0];
        #pragma unroll
        for (int w = 1; w < 8; ++w) if (psh[w] > m) m = psh[w];
        #pragma unroll
        for (int r = 0; r < NREP; ++r)
          __hip_atomic_store(&parts[r*256 + wg], m, RLX, AGT);
      }
      // gather 256 partials from my replica (32 pollers per line), local reduce
      u64 myp = 0;
      if (tid < 256){
        u64 e = __hip_atomic_load(&myParts[tid], RLX, AGT);
        while ((unsigned)((e>>12) & 0xFFFu) != (tag & 0xFFFu)){
          __builtin_amdgcn_s_sleep(1);
          e = __hip_atomic_load(&myParts[tid], RLX, AGT);
        }
        myp = e;
      }
      if (wave < 4){
        #pragma unroll
        for (int off = 32; off; off >>= 1){
          u64 o = __shfl_xor(myp, off, 64);
          if (o > myp) myp = o;
        }
        if (lane == 0) pmx[wave] = myp;
      }
      __syncthreads();
      u64 m = pmx[0];
      if (pmx[1] > m) m = pmx[1];
      if (pmx[2] > m) m = pmx[2];
      if (pmx[3] > m) m = pmx[3];
      k = 4095 - (int)(m & 0xFFFull);
    }

    // ===== E: decision (replicated in every WG) =====
    bool stop = (k == 0) || (sa >= MAX_SYM);
    if (!stop){
      if (wg == 0 && tid == 0) out[(size_t)NSTEPS*VOCAB + cnt] = (float)k;
      if (tid < nj){ c0c[tid] = c0p[tid]; c1c[tid] = c1p[tid]; }
      cnt++; sa++; last = k; cur ^= 1; reuse = false;
    } else {
      sa = 0; t++; reuse = true;
      if (t >= timesteps) done = true;
    }
    __syncthreads();
  }

  // labels tail (-1) and cnt
  size_t lab = (size_t)NSTEPS*VOCAB;
  int gidx = wg*NTHR + tid;
  for (int i = cnt + gidx; i < NSTEPS; i += NWG*NTHR) out[lab + i] = -1.f;
  if (wg == 0 && tid == 0) out[lab + NSTEPS] = (float)cnt;
}

extern "C" void kernel_launch(void* const* d_in, const int* in_sizes, int n_in,
                              void* d_out, int out_size, void* d_ws, size_t ws_size,
                              hipStream_t stream) {
  const float* enc  = (const float*)d_in[0];
  const int*   olen = (const int*)  d_in[1];
  const float* emb  = (const float*)d_in[2];
  const float* Wih0 = (const float*)d_in[3];
  const float* Whh0 = (const float*)d_in[4];
  const float* b0   = (const float*)d_in[5];
  const float* Wih1 = (const float*)d_in[6];
  const float* Whh1 = (const float*)d_in[7];
  const float* b1   = (const float*)d_in[8];
  const float* Wj1  = (const float*)d_in[9];
  const float* bj1  = (const float*)d_in[10];
  const float* Wj2  = (const float*)d_in[11];
  const float* bj2  = (const float*)d_in[12];
  float* out = (float*)d_out;

  u64* parts = (u64*)d_ws;
  u64* bufsT = (u64*)((char*)d_ws + 16384);
  u64* hidT  = (u64*)((char*)d_ws + 98304);

  init_ws<<<64, 256, 0, stream>>>((unsigned*)d_ws);

  void* args[] = {&enc,&olen,&emb,&Wih0,&Whh0,&b0,&Wih1,&Whh1,&b1,
                  &Wj1,&bj1,&Wj2,&bj2,&out,&parts,&bufsT,&hidT};
  hipLaunchCooperativeKernel((const void*)rnnt_decode, dim3(NWG), dim3(NTHR),
                             args, 0, stream);
}